// Round 2
// baseline (326.084 us; speedup 1.0000x reference)
//
#include <hip/hip_runtime.h>

typedef unsigned short u16;
typedef __attribute__((ext_vector_type(8))) short bf16x8;
typedef __attribute__((ext_vector_type(4))) float f32x4;

#define GPTR(p) ((const __attribute__((address_space(1))) void*)(p))
#define SPTR(p) ((__attribute__((address_space(3))) void*)(p))

// ---------- sizes ----------
#define L_SEQ 1024
#define DIM 1024
#define D_INNER 2048
#define D_STATE 64
#define N_HEADS 32
#define NPROJ 4256
#define NPROJ_PAD 4352   // 34 * 128
#define COL_Z 0
#define COL_X 2048
#define COL_B 4096
#define COL_C 4160
#define COL_DT 4224

__device__ __forceinline__ u16 f2bf(float f) {
    unsigned int u = __float_as_uint(f);
    u = u + 0x7fffu + ((u >> 16) & 1u);   // RNE
    return (u16)(u >> 16);
}
__device__ __forceinline__ float bf2f(u16 h) {
    unsigned int u = ((unsigned int)h) << 16;
    return __uint_as_float(u);
}

// ---------- cast f32 -> bf16 (hi only) with zero pad ----------
__global__ __launch_bounds__(256)
void cast_pad_kernel(const float* __restrict__ in, u16* __restrict__ out,
                     int n_in, int n_out)
{
    int i = (blockIdx.x * 256 + threadIdx.x) * 4;
    if (i >= n_out) return;
    float4 v = make_float4(0.f, 0.f, 0.f, 0.f);
    if (i < n_in) v = *(const float4*)&in[i];
    u16 o[4] = { f2bf(v.x), f2bf(v.y), f2bf(v.z), f2bf(v.w) };
    *(ushort4*)&out[i] = *(ushort4*)o;
}

// ---------- cast f32 -> bf16 hi + residual lo, with zero pad ----------
__global__ __launch_bounds__(256)
void cast_split_kernel(const float* __restrict__ in, u16* __restrict__ hi,
                       u16* __restrict__ lo, int n_in, int n_out)
{
    int i = (blockIdx.x * 256 + threadIdx.x) * 4;
    if (i >= n_out) return;
    float4 v = make_float4(0.f, 0.f, 0.f, 0.f);
    if (i < n_in) v = *(const float4*)&in[i];
    float vs[4] = { v.x, v.y, v.z, v.w };
    u16 oh[4], ol[4];
    #pragma unroll
    for (int j = 0; j < 4; ++j) {
        oh[j] = f2bf(vs[j]);
        ol[j] = f2bf(vs[j] - bf2f(oh[j]));
    }
    *(ushort4*)&hi[i] = *(ushort4*)oh;
    *(ushort4*)&lo[i] = *(ushort4*)ol;
}

// ---------- bf16 MFMA GEMM: C[M,N] = A[M,K] * B[N,K]^T (m97-style) ----------
// Col-blocks >= precise_from use 3-pass split-bf16 (hi*hi + hi*lo + lo*hi).
__global__ __launch_bounds__(256, 2)
void gemm_bt128(const u16* __restrict__ Ah, const u16* __restrict__ Al,
                const u16* __restrict__ Bh, const u16* __restrict__ Bl,
                float* __restrict__ C, int K, int ldc, int precise_from)
{
    __shared__ u16 As[128 * 32];
    __shared__ u16 Bs[128 * 32];
    __shared__ u16 AsL[128 * 32];
    __shared__ u16 BsL[128 * 32];
    const int tid  = threadIdx.x;
    const int wave = tid >> 6;
    const int lane = tid & 63;
    const int row0 = blockIdx.y * 128;
    const int col0 = blockIdx.x * 128;
    const int wm = (wave >> 1) * 64;
    const int wn = (wave & 1) * 64;
    const bool precise = ((int)blockIdx.x >= precise_from);

    f32x4 acc[4][4] = {};

    const int r15 = lane & 15;
    const int ko  = (lane >> 4) * 8;

    for (int kt = 0; kt < K; kt += 32) {
        #pragma unroll
        for (int call = 0; call < 2; ++call) {
            const int ob = call * 4096 + wave * 1024 + lane * 16; // byte off in 8KB tile
            const int rr = ob >> 6;            // tile row (64B per row)
            const int kk = (ob & 63) >> 1;     // u16 col within row
            const size_t goff = (size_t)(row0 + rr) * K + kt + kk;
            const size_t gofb = (size_t)(col0 + rr) * K + kt + kk;
            const int lofs = call * 2048 + wave * 512;  // wave-uniform LDS base (u16)
            __builtin_amdgcn_global_load_lds(GPTR(Ah + goff), SPTR(As + lofs), 16, 0, 0);
            __builtin_amdgcn_global_load_lds(GPTR(Bh + gofb), SPTR(Bs + lofs), 16, 0, 0);
            if (precise) {
                __builtin_amdgcn_global_load_lds(GPTR(Al + goff), SPTR(AsL + lofs), 16, 0, 0);
                __builtin_amdgcn_global_load_lds(GPTR(Bl + gofb), SPTR(BsL + lofs), 16, 0, 0);
            }
        }
        __syncthreads();
        bf16x8 av[4], bv[4];
        #pragma unroll
        for (int i = 0; i < 4; ++i)
            av[i] = *(const bf16x8*)&As[(wm + i * 16 + r15) * 32 + ko];
        #pragma unroll
        for (int j = 0; j < 4; ++j)
            bv[j] = *(const bf16x8*)&Bs[(wn + j * 16 + r15) * 32 + ko];
        if (precise) {
            bf16x8 avl[4], bvl[4];
            #pragma unroll
            for (int i = 0; i < 4; ++i)
                avl[i] = *(const bf16x8*)&AsL[(wm + i * 16 + r15) * 32 + ko];
            #pragma unroll
            for (int j = 0; j < 4; ++j)
                bvl[j] = *(const bf16x8*)&BsL[(wn + j * 16 + r15) * 32 + ko];
            #pragma unroll
            for (int i = 0; i < 4; ++i)
                #pragma unroll
                for (int j = 0; j < 4; ++j) {
                    acc[i][j] = __builtin_amdgcn_mfma_f32_16x16x32_bf16(av[i],  bv[j],  acc[i][j], 0, 0, 0);
                    acc[i][j] = __builtin_amdgcn_mfma_f32_16x16x32_bf16(av[i],  bvl[j], acc[i][j], 0, 0, 0);
                    acc[i][j] = __builtin_amdgcn_mfma_f32_16x16x32_bf16(avl[i], bv[j],  acc[i][j], 0, 0, 0);
                }
        } else {
            #pragma unroll
            for (int i = 0; i < 4; ++i)
                #pragma unroll
                for (int j = 0; j < 4; ++j)
                    acc[i][j] = __builtin_amdgcn_mfma_f32_16x16x32_bf16(av[i], bv[j], acc[i][j], 0, 0, 0);
        }
        __syncthreads();
    }

    const int cl = lane & 15;
    const int rg = (lane >> 4) * 4;
    #pragma unroll
    for (int i = 0; i < 4; ++i)
        #pragma unroll
        for (int j = 0; j < 4; ++j)
            #pragma unroll
            for (int reg = 0; reg < 4; ++reg) {
                const int rrow = row0 + wm + i * 16 + rg + reg;
                const int ccol = col0 + wn + j * 16 + cl;
                C[(size_t)rrow * ldc + ccol] = acc[i][j][reg];
            }
}

// ---------- causal depthwise conv(4) + SiLU, plus dt softplus ----------
__global__ __launch_bounds__(256)
void conv_silu_kernel(const float* __restrict__ P,
                      const float* __restrict__ Wc,
                      const float* __restrict__ bc,
                      const float* __restrict__ dtb,
                      float* __restrict__ xconv,
                      float* __restrict__ dts)
{
    const int t = blockIdx.x;
    const int tid = threadIdx.x;
    const int c0 = tid * 8;

    float acc[8];
    #pragma unroll
    for (int j = 0; j < 8; ++j) acc[j] = bc[c0 + j];

    #pragma unroll
    for (int k = 0; k < 4; ++k) {
        const int tt = t - 3 + k;
        if (tt >= 0) {
            const float* row = P + (size_t)tt * NPROJ_PAD + COL_X + c0;
            float4 a0 = *(const float4*)row;
            float4 a1 = *(const float4*)(row + 4);
            float xv[8] = { a0.x, a0.y, a0.z, a0.w, a1.x, a1.y, a1.z, a1.w };
            #pragma unroll
            for (int j = 0; j < 8; ++j)
                acc[j] = fmaf(xv[j], Wc[(c0 + j) * 4 + k], acc[j]);
        }
    }
    float o[8];
    #pragma unroll
    for (int j = 0; j < 8; ++j) {
        const float v = acc[j];
        o[j] = v / (1.f + __expf(-v));         // SiLU
    }
    float* dst = xconv + (size_t)t * D_INNER + c0;
    *(float4*)dst       = make_float4(o[0], o[1], o[2], o[3]);
    *(float4*)(dst + 4) = make_float4(o[4], o[5], o[6], o[7]);

    if (tid < N_HEADS) {
        const float v = P[(size_t)t * NPROJ_PAD + COL_DT + tid] + dtb[tid];
        dts[t * N_HEADS + tid] = (v > 15.f) ? v : __logf(1.f + __expf(v));
    }
}

// ---------- selective scan: one wave per (h,d), lane = state index n ----------
__global__ __launch_bounds__(64, 2)
void scan_kernel(const float* __restrict__ P,
                 const float* __restrict__ xconv,
                 const float* __restrict__ dts,
                 const float* __restrict__ A_log,
                 const float* __restrict__ Dp,
                 float* __restrict__ yg)
{
    __shared__ float ptile[64][65];   // [t_local][n], pad -> conflict-free both phases
    const int hd = blockIdx.x;        // 0..2047
    const int h  = hd >> 6;
    const int lane = threadIdx.x;     // n = 0..63

    const float Av = -__expf(A_log[(size_t)hd * 64 + lane]);
    const float Dv = Dp[hd];
    float s = 0.f;
    float xsave = 0.f;

    for (int t0 = 0; t0 < L_SEQ; t0 += 64) {
        #pragma unroll 8
        for (int tl = 0; tl < 64; ++tl) {
            const int t = t0 + tl;
            const float dt = dts[t * N_HEADS + h];                      // scalar (uniform)
            const float Bv = P[(size_t)t * NPROJ_PAD + COL_B + lane];   // coalesced
            const float Cv = P[(size_t)t * NPROJ_PAD + COL_C + lane];
            const float xv = xconv[(size_t)t * D_INNER + hd];           // scalar (uniform)
            const float a  = __expf(dt * Av);
            s = fmaf(a, s, Bv * xv);
            ptile[tl][lane] = s * Cv;
            xsave = (lane == tl) ? xv : xsave;   // each lane keeps its own step's x
        }
        __syncthreads();
        float ysum = 0.f;
        #pragma unroll
        for (int n = 0; n < 64; ++n) ysum += ptile[lane][n];
        const int t = t0 + lane;
        const float z = P[(size_t)t * NPROJ_PAD + COL_Z + hd];
        const float yv = ysum + Dv * xsave;
        const float sig = 1.f / (1.f + __expf(-z));
        yg[(size_t)t * D_INNER + hd] = yv * (z * sig);   // skip + gate fused
        __syncthreads();
    }
}

// ---------- RMSNorm + cast to bf16 ----------
__global__ __launch_bounds__(256)
void rmsnorm_kernel(const float* __restrict__ yg,
                    const float* __restrict__ nw,
                    u16* __restrict__ Yb)
{
    __shared__ float red[4];
    const int row = blockIdx.x;
    const int tid = threadIdx.x;
    const int c0 = tid * 8;
    const float* p = yg + (size_t)row * D_INNER + c0;
    const float4 v0 = *(const float4*)p;
    const float4 v1 = *(const float4*)(p + 4);
    float ss = v0.x*v0.x + v0.y*v0.y + v0.z*v0.z + v0.w*v0.w
             + v1.x*v1.x + v1.y*v1.y + v1.z*v1.z + v1.w*v1.w;
    #pragma unroll
    for (int off = 32; off > 0; off >>= 1) ss += __shfl_xor(ss, off);
    const int wave = tid >> 6;
    if ((tid & 63) == 0) red[wave] = ss;
    __syncthreads();
    const float total = red[0] + red[1] + red[2] + red[3];
    const float scale = rsqrtf(total * (1.f / D_INNER) + 1e-6f);
    const float vals[8] = { v0.x, v0.y, v0.z, v0.w, v1.x, v1.y, v1.z, v1.w };
    u16 o[8];
    #pragma unroll
    for (int j = 0; j < 8; ++j)
        o[j] = f2bf(vals[j] * scale * nw[c0 + j]);
    *(uint4*)&Yb[(size_t)row * D_INNER + c0] = *(uint4*)o;
}

// ---------- launcher ----------
extern "C" void kernel_launch(void* const* d_in, const int* in_sizes, int n_in,
                              void* d_out, int out_size, void* d_ws, size_t ws_size,
                              hipStream_t stream)
{
    const float* x      = (const float*)d_in[0];
    const float* W_in   = (const float*)d_in[1];
    const float* W_conv = (const float*)d_in[2];
    const float* b_conv = (const float*)d_in[3];
    const float* A_log  = (const float*)d_in[4];
    const float* Dp     = (const float*)d_in[5];
    const float* dt_bias= (const float*)d_in[6];
    const float* norm_w = (const float*)d_in[7];
    const float* W_out  = (const float*)d_in[8];
    float* out = (float*)d_out;

    char* w = (char*)d_ws;
    u16*   xb_hi  = (u16*)(w);                         //  2.0 MiB @ 0
    u16*   xb_lo  = (u16*)(w + (2u  << 20));           //  2.0 MiB
    u16*   Winb   = (u16*)(w + (4u  << 20));           //  8.5 MiB (4352x1024)
    u16*   Winb_lo= (u16*)(w + (13u << 20));           //  0.5 MiB (rows 4096..4352)
    u16*   Woutb  = (u16*)(w + (14u << 20));           //  4.0 MiB
    float* P      = (float*)(w + (18u << 20));         // 17.0 MiB (1024x4352)
    float* xconv  = (float*)(w + (35u << 20));         //  8.0 MiB
    float* dts    = (float*)(w + (43u << 20));         //  0.13 MiB
    float* yg     = (float*)(w + (44u << 20));         //  8.0 MiB
    u16*   Yb     = (u16*)(w + (52u << 20));           //  4.0 MiB

    // virtual base so precise GEMM blocks index Winb_lo with global row numbers
    const u16* Winb_lo_virt = Winb_lo - (size_t)4096 * DIM;

    // 1. casts
    cast_split_kernel<<<dim3((DIM * L_SEQ / 4 + 255) / 256), 256, 0, stream>>>(
        x, xb_hi, xb_lo, DIM * L_SEQ, DIM * L_SEQ);
    cast_pad_kernel<<<dim3((NPROJ_PAD * DIM / 4 + 255) / 256), 256, 0, stream>>>(
        W_in, Winb, NPROJ * DIM, NPROJ_PAD * DIM);
    cast_split_kernel<<<dim3((256 * DIM / 4 + 255) / 256), 256, 0, stream>>>(
        W_in + (size_t)4096 * DIM, Winb + (size_t)4096 * DIM, Winb_lo,
        (NPROJ - 4096) * DIM, 256 * DIM);
    cast_pad_kernel<<<dim3((DIM * D_INNER / 4 + 255) / 256), 256, 0, stream>>>(
        W_out, Woutb, DIM * D_INNER, DIM * D_INNER);

    // 2. in-projection GEMM: P = x @ W_in^T (1024 x 4352); B/C/dt cols 3-pass precise
    gemm_bt128<<<dim3(NPROJ_PAD / 128, L_SEQ / 128), 256, 0, stream>>>(
        xb_hi, xb_lo, Winb, Winb_lo_virt, P, DIM, NPROJ_PAD, 32);

    // 3. depthwise causal conv + SiLU + dt softplus
    conv_silu_kernel<<<dim3(L_SEQ), 256, 0, stream>>>(
        P, W_conv, b_conv, dt_bias, xconv, dts);

    // 4. selective scan (+ skip + gate)
    scan_kernel<<<dim3(D_INNER), 64, 0, stream>>>(
        P, xconv, dts, A_log, Dp, yg);

    // 5. RMSNorm + bf16 cast
    rmsnorm_kernel<<<dim3(L_SEQ), 256, 0, stream>>>(yg, norm_w, Yb);

    // 6. out-projection GEMM: out = Y @ W_out^T (1024 x 1024)
    gemm_bt128<<<dim3(DIM / 128, L_SEQ / 128), 256, 0, stream>>>(
        Yb, (const u16*)nullptr, Woutb, (const u16*)nullptr, out, D_INNER, DIM, 9999);
}

// Round 3
// 277.843 us; speedup vs baseline: 1.1736x; 1.1736x over previous
//
#include <hip/hip_runtime.h>

typedef unsigned short u16;
typedef __attribute__((ext_vector_type(8))) short bf16x8;
typedef __attribute__((ext_vector_type(4))) float f32x4;

#define GPTR(p) ((const __attribute__((address_space(1))) void*)(p))
#define SPTR(p) ((__attribute__((address_space(3))) void*)(p))

// ---------- sizes ----------
#define L_SEQ 1024
#define DIM 1024
#define D_INNER 2048
#define D_STATE 64
#define N_HEADS 32
#define NPROJ 4256
#define NPROJ_PAD 4352   // 34 * 128
#define COL_Z 0
#define COL_X 2048
#define COL_B 4096
#define COL_C 4160
#define COL_DT 4224
#define NCHUNK 16
#define QCH 64           // chunk length

__device__ __forceinline__ u16 f2bf(float f) {
    unsigned int u = __float_as_uint(f);
    u = u + 0x7fffu + ((u >> 16) & 1u);   // RNE
    return (u16)(u >> 16);
}
__device__ __forceinline__ float bf2f(u16 h) {
    unsigned int u = ((unsigned int)h) << 16;
    return __uint_as_float(u);
}

// ---------- cast f32 -> bf16 (hi only) with zero pad ----------
__global__ __launch_bounds__(256)
void cast_pad_kernel(const float* __restrict__ in, u16* __restrict__ out,
                     int n_in, int n_out)
{
    int i = (blockIdx.x * 256 + threadIdx.x) * 4;
    if (i >= n_out) return;
    float4 v = make_float4(0.f, 0.f, 0.f, 0.f);
    if (i < n_in) v = *(const float4*)&in[i];
    u16 o[4] = { f2bf(v.x), f2bf(v.y), f2bf(v.z), f2bf(v.w) };
    *(ushort4*)&out[i] = *(ushort4*)o;
}

// ---------- cast f32 -> bf16 hi + residual lo, with zero pad ----------
__global__ __launch_bounds__(256)
void cast_split_kernel(const float* __restrict__ in, u16* __restrict__ hi,
                       u16* __restrict__ lo, int n_in, int n_out)
{
    int i = (blockIdx.x * 256 + threadIdx.x) * 4;
    if (i >= n_out) return;
    float4 v = make_float4(0.f, 0.f, 0.f, 0.f);
    if (i < n_in) v = *(const float4*)&in[i];
    float vs[4] = { v.x, v.y, v.z, v.w };
    u16 oh[4], ol[4];
    #pragma unroll
    for (int j = 0; j < 4; ++j) {
        oh[j] = f2bf(vs[j]);
        ol[j] = f2bf(vs[j] - bf2f(oh[j]));
    }
    *(ushort4*)&hi[i] = *(ushort4*)oh;
    *(ushort4*)&lo[i] = *(ushort4*)ol;
}

// ---------- bf16 MFMA GEMM: C[M,N] = A[M,K] * B[N,K]^T (m97-style) ----------
// Col-blocks >= precise_from use 3-pass split-bf16 (hi*hi + hi*lo + lo*hi).
__global__ __launch_bounds__(256, 2)
void gemm_bt128(const u16* __restrict__ Ah, const u16* __restrict__ Al,
                const u16* __restrict__ Bh, const u16* __restrict__ Bl,
                float* __restrict__ C, int K, int ldc, int precise_from)
{
    __shared__ u16 As[128 * 32];
    __shared__ u16 Bs[128 * 32];
    __shared__ u16 AsL[128 * 32];
    __shared__ u16 BsL[128 * 32];
    const int tid  = threadIdx.x;
    const int wave = tid >> 6;
    const int lane = tid & 63;
    const int row0 = blockIdx.y * 128;
    const int col0 = blockIdx.x * 128;
    const int wm = (wave >> 1) * 64;
    const int wn = (wave & 1) * 64;
    const bool precise = ((int)blockIdx.x >= precise_from);

    f32x4 acc[4][4] = {};

    const int r15 = lane & 15;
    const int ko  = (lane >> 4) * 8;

    for (int kt = 0; kt < K; kt += 32) {
        #pragma unroll
        for (int call = 0; call < 2; ++call) {
            const int ob = call * 4096 + wave * 1024 + lane * 16; // byte off in 8KB tile
            const int rr = ob >> 6;            // tile row (64B per row)
            const int kk = (ob & 63) >> 1;     // u16 col within row
            const size_t goff = (size_t)(row0 + rr) * K + kt + kk;
            const size_t gofb = (size_t)(col0 + rr) * K + kt + kk;
            const int lofs = call * 2048 + wave * 512;  // wave-uniform LDS base (u16)
            __builtin_amdgcn_global_load_lds(GPTR(Ah + goff), SPTR(As + lofs), 16, 0, 0);
            __builtin_amdgcn_global_load_lds(GPTR(Bh + gofb), SPTR(Bs + lofs), 16, 0, 0);
            if (precise) {
                __builtin_amdgcn_global_load_lds(GPTR(Al + goff), SPTR(AsL + lofs), 16, 0, 0);
                __builtin_amdgcn_global_load_lds(GPTR(Bl + gofb), SPTR(BsL + lofs), 16, 0, 0);
            }
        }
        __syncthreads();
        bf16x8 av[4], bv[4];
        #pragma unroll
        for (int i = 0; i < 4; ++i)
            av[i] = *(const bf16x8*)&As[(wm + i * 16 + r15) * 32 + ko];
        #pragma unroll
        for (int j = 0; j < 4; ++j)
            bv[j] = *(const bf16x8*)&Bs[(wn + j * 16 + r15) * 32 + ko];
        if (precise) {
            bf16x8 avl[4], bvl[4];
            #pragma unroll
            for (int i = 0; i < 4; ++i)
                avl[i] = *(const bf16x8*)&AsL[(wm + i * 16 + r15) * 32 + ko];
            #pragma unroll
            for (int j = 0; j < 4; ++j)
                bvl[j] = *(const bf16x8*)&BsL[(wn + j * 16 + r15) * 32 + ko];
            #pragma unroll
            for (int i = 0; i < 4; ++i)
                #pragma unroll
                for (int j = 0; j < 4; ++j) {
                    acc[i][j] = __builtin_amdgcn_mfma_f32_16x16x32_bf16(av[i],  bv[j],  acc[i][j], 0, 0, 0);
                    acc[i][j] = __builtin_amdgcn_mfma_f32_16x16x32_bf16(av[i],  bvl[j], acc[i][j], 0, 0, 0);
                    acc[i][j] = __builtin_amdgcn_mfma_f32_16x16x32_bf16(avl[i], bv[j],  acc[i][j], 0, 0, 0);
                }
        } else {
            #pragma unroll
            for (int i = 0; i < 4; ++i)
                #pragma unroll
                for (int j = 0; j < 4; ++j)
                    acc[i][j] = __builtin_amdgcn_mfma_f32_16x16x32_bf16(av[i], bv[j], acc[i][j], 0, 0, 0);
        }
        __syncthreads();
    }

    const int cl = lane & 15;
    const int rg = (lane >> 4) * 4;
    #pragma unroll
    for (int i = 0; i < 4; ++i)
        #pragma unroll
        for (int j = 0; j < 4; ++j)
            #pragma unroll
            for (int reg = 0; reg < 4; ++reg) {
                const int rrow = row0 + wm + i * 16 + rg + reg;
                const int ccol = col0 + wn + j * 16 + cl;
                C[(size_t)rrow * ldc + ccol] = acc[i][j][reg];
            }
}

// ---------- causal depthwise conv(4) + SiLU ----------
__global__ __launch_bounds__(256)
void conv_silu_kernel(const float* __restrict__ P,
                      const float* __restrict__ Wc,
                      const float* __restrict__ bc,
                      float* __restrict__ xconv)
{
    const int t = blockIdx.x;
    const int tid = threadIdx.x;
    const int c0 = tid * 8;

    float acc[8];
    #pragma unroll
    for (int j = 0; j < 8; ++j) acc[j] = bc[c0 + j];

    #pragma unroll
    for (int k = 0; k < 4; ++k) {
        const int tt = t - 3 + k;
        if (tt >= 0) {
            const float* row = P + (size_t)tt * NPROJ_PAD + COL_X + c0;
            float4 a0 = *(const float4*)row;
            float4 a1 = *(const float4*)(row + 4);
            float xv[8] = { a0.x, a0.y, a0.z, a0.w, a1.x, a1.y, a1.z, a1.w };
            #pragma unroll
            for (int j = 0; j < 8; ++j)
                acc[j] = fmaf(xv[j], Wc[(c0 + j) * 4 + k], acc[j]);
        }
    }
    float o[8];
    #pragma unroll
    for (int j = 0; j < 8; ++j) {
        const float v = acc[j];
        o[j] = v / (1.f + __expf(-v));         // SiLU
    }
    float* dst = xconv + (size_t)t * D_INNER + c0;
    *(float4*)dst       = make_float4(o[0], o[1], o[2], o[3]);
    *(float4*)(dst + 4) = make_float4(o[4], o[5], o[6], o[7]);
}

// ---------- dt softplus + per-chunk inclusive cumsum (one wave per head) ----------
__global__ __launch_bounds__(64)
void dtscan_kernel(const float* __restrict__ P, const float* __restrict__ dtb,
                   float* __restrict__ dts, float* __restrict__ g)
{
    const int h = blockIdx.x;
    const int lane = threadIdx.x;
    const float bias = dtb[h];
    for (int c = 0; c < NCHUNK; ++c) {
        const int t = c * QCH + lane;
        float v = P[(size_t)t * NPROJ_PAD + COL_DT + h] + bias;
        v = (v > 15.f) ? v : __logf(1.f + __expf(v));
        dts[t * N_HEADS + h] = v;
        // inclusive scan across 64 lanes (restarts each chunk)
        #pragma unroll
        for (int off = 1; off < 64; off <<= 1) {
            const float u = __shfl_up(v, off);
            if (lane >= off) v += u;
        }
        g[t * N_HEADS + h] = v;
    }
}

// ---------- pass 1: local chunk scan. lane = n; wave = (hd, chunk) ----------
__global__ __launch_bounds__(256, 4)
void scan_local_kernel(const float* __restrict__ P,
                       const float* __restrict__ xconv,
                       const float* __restrict__ dts,
                       const float* __restrict__ A_log,
                       const float* __restrict__ Dp,
                       float* __restrict__ yg,    // [hd][t] partial
                       float* __restrict__ S)     // [hd][chunk][n] local final state
{
    __shared__ float ptile[4][32][65];
    const int wv = threadIdx.x >> 6;
    const int lane = threadIdx.x & 63;
    const int w = blockIdx.x * 4 + wv;
    const int hd = w >> 4;
    const int chunk = w & 15;
    const int h = hd >> 6;
    const int t0 = chunk * QCH;

    const float Av = -__expf(A_log[(size_t)hd * 64 + lane]);
    const float Dv = Dp[hd];
    float s = 0.f;

    #pragma unroll
    for (int p = 0; p < 2; ++p) {
        float xs = 0.f;
        #pragma unroll 8
        for (int i = 0; i < 32; ++i) {
            const int t = t0 + p * 32 + i;
            const float dt = dts[t * N_HEADS + h];
            const float Bv = P[(size_t)t * NPROJ_PAD + COL_B + lane];
            const float Cv = P[(size_t)t * NPROJ_PAD + COL_C + lane];
            const float xv = xconv[(size_t)t * D_INNER + hd];
            const float a  = __expf(dt * Av);
            s = fmaf(a, s, Bv * xv);
            ptile[wv][i][lane] = s * Cv;
            if (i == (lane & 31)) xs = xv;
        }
        __syncthreads();
        float ss = 0.f;
        const int tr = lane & 31;
        const int nh = (lane >> 5) * 32;
        #pragma unroll
        for (int n = 0; n < 32; ++n) ss += ptile[wv][tr][nh + n];
        ss += __shfl_xor(ss, 32);
        if (lane < 32) {
            const int t = t0 + p * 32 + lane;
            yg[(size_t)hd * L_SEQ + t] = ss + Dv * xs;   // partial y + skip
        }
        __syncthreads();
    }
    S[((size_t)hd * NCHUNK + chunk) * 64 + lane] = s;
}

// ---------- pass 2: chunk-state carry (in place: S -> chunk entry states) ----------
__global__ __launch_bounds__(256)
void chunk_combine_kernel(const float* __restrict__ A_log,
                          const float* __restrict__ g,
                          float* __restrict__ S)
{
    const int tid = blockIdx.x * 256 + threadIdx.x;   // hd*64 + n
    const int hd = tid >> 6;
    const int n  = tid & 63;
    const int h  = hd >> 6;
    const float Av = -__expf(A_log[(size_t)hd * 64 + n]);
    float H = 0.f;
    for (int c = 0; c < NCHUNK; ++c) {
        const float Gc = g[(c * QCH + QCH - 1) * N_HEADS + h];  // chunk dt total
        const size_t idx = ((size_t)hd * NCHUNK + c) * 64 + n;
        const float Sl = S[idx];
        S[idx] = H;                       // entry state for chunk c
        H = __expf(Av * Gc) * H + Sl;
    }
}

// ---------- pass 3: cross-chunk contribution y += C~ . H_entry ----------
__global__ __launch_bounds__(256, 4)
void scan_cross_kernel(const float* __restrict__ P,
                       const float* __restrict__ g,
                       const float* __restrict__ A_log,
                       const float* __restrict__ S,   // entry states
                       float* __restrict__ yg)
{
    __shared__ float ptile[4][32][65];
    const int wv = threadIdx.x >> 6;
    const int lane = threadIdx.x & 63;
    const int w = blockIdx.x * 4 + wv;
    const int hd = w >> 4;
    const int chunk = w & 15;
    const int h = hd >> 6;
    const int t0 = chunk * QCH;

    const float Av = -__expf(A_log[(size_t)hd * 64 + lane]);
    const float Hn = S[((size_t)hd * NCHUNK + chunk) * 64 + lane];

    #pragma unroll
    for (int p = 0; p < 2; ++p) {
        #pragma unroll 8
        for (int i = 0; i < 32; ++i) {
            const int t = t0 + p * 32 + i;
            const float Cv = P[(size_t)t * NPROJ_PAD + COL_C + lane];
            const float gt = g[t * N_HEADS + h];
            ptile[wv][i][lane] = Cv * (Hn * __expf(Av * gt));
        }
        __syncthreads();
        float ss = 0.f;
        const int tr = lane & 31;
        const int nh = (lane >> 5) * 32;
        #pragma unroll
        for (int n = 0; n < 32; ++n) ss += ptile[wv][tr][nh + n];
        ss += __shfl_xor(ss, 32);
        if (lane < 32) {
            const int t = t0 + p * 32 + lane;
            yg[(size_t)hd * L_SEQ + t] += ss;
        }
        __syncthreads();
    }
}

// ---------- RMSNorm + gate + cast to bf16 ----------
__global__ __launch_bounds__(256)
void rmsnorm_kernel(const float* __restrict__ yg,   // [hd][t]
                    const float* __restrict__ P,    // z columns
                    const float* __restrict__ nw,
                    u16* __restrict__ Yb)           // [t][hd] bf16
{
    __shared__ float red[4];
    const int t = blockIdx.x;
    const int tid = threadIdx.x;
    const int c0 = tid * 8;
    const float* zrow = P + (size_t)t * NPROJ_PAD + COL_Z + c0;
    const float4 z0 = *(const float4*)zrow;
    const float4 z1 = *(const float4*)(zrow + 4);
    const float zz[8] = { z0.x, z0.y, z0.z, z0.w, z1.x, z1.y, z1.z, z1.w };
    float v[8];
    float ss = 0.f;
    #pragma unroll
    for (int j = 0; j < 8; ++j) {
        const float yv = yg[(size_t)(c0 + j) * L_SEQ + t];   // strided read
        const float z = zz[j];
        const float gated = yv * (z / (1.f + __expf(-z)));
        v[j] = gated;
        ss += gated * gated;
    }
    #pragma unroll
    for (int off = 32; off > 0; off >>= 1) ss += __shfl_xor(ss, off);
    const int wave = tid >> 6;
    if ((tid & 63) == 0) red[wave] = ss;
    __syncthreads();
    const float total = red[0] + red[1] + red[2] + red[3];
    const float scale = rsqrtf(total * (1.f / D_INNER) + 1e-6f);
    u16 o[8];
    #pragma unroll
    for (int j = 0; j < 8; ++j)
        o[j] = f2bf(v[j] * scale * nw[c0 + j]);
    *(uint4*)&Yb[(size_t)t * D_INNER + c0] = *(uint4*)o;
}

// ---------- launcher ----------
extern "C" void kernel_launch(void* const* d_in, const int* in_sizes, int n_in,
                              void* d_out, int out_size, void* d_ws, size_t ws_size,
                              hipStream_t stream)
{
    const float* x      = (const float*)d_in[0];
    const float* W_in   = (const float*)d_in[1];
    const float* W_conv = (const float*)d_in[2];
    const float* b_conv = (const float*)d_in[3];
    const float* A_log  = (const float*)d_in[4];
    const float* Dp     = (const float*)d_in[5];
    const float* dt_bias= (const float*)d_in[6];
    const float* norm_w = (const float*)d_in[7];
    const float* W_out  = (const float*)d_in[8];
    float* out = (float*)d_out;

    char* w = (char*)d_ws;
    u16*   xb_hi  = (u16*)(w);                         //  2.0 MiB @ 0  (dead after GEMM1)
    u16*   xb_lo  = (u16*)(w + (2u  << 20));           //  2.0 MiB     (dead after GEMM1)
    u16*   Yb     = (u16*)(w);                         //  4.0 MiB (overlaps xb_*)
    u16*   Winb   = (u16*)(w + (4u  << 20));           //  8.5 MiB     (dead after GEMM1)
    float* S      = (float*)(w + (4u  << 20));         //  8.4 MiB (overlaps Winb)
    u16*   Winb_lo= (u16*)(w + (13u << 20));           //  0.5 MiB
    u16*   Woutb  = (u16*)(w + (14u << 20));           //  4.0 MiB
    float* P      = (float*)(w + (18u << 20));         // 17.0 MiB (1024x4352)
    float* xconv  = (float*)(w + (35u << 20));         //  8.0 MiB
    float* dts    = (float*)(w + (43u << 20));         //  0.13 MiB
    float* g      = (float*)(w + (44u << 20));         //  0.13 MiB
    float* yg     = (float*)(w + (45u << 20));         //  8.0 MiB [hd][t]

    // virtual base so precise GEMM blocks index Winb_lo with global row numbers
    const u16* Winb_lo_virt = Winb_lo - (size_t)4096 * DIM;

    // 1. casts
    cast_split_kernel<<<dim3((DIM * L_SEQ / 4 + 255) / 256), 256, 0, stream>>>(
        x, xb_hi, xb_lo, DIM * L_SEQ, DIM * L_SEQ);
    cast_pad_kernel<<<dim3((NPROJ_PAD * DIM / 4 + 255) / 256), 256, 0, stream>>>(
        W_in, Winb, NPROJ * DIM, NPROJ_PAD * DIM);
    cast_split_kernel<<<dim3((256 * DIM / 4 + 255) / 256), 256, 0, stream>>>(
        W_in + (size_t)4096 * DIM, Winb + (size_t)4096 * DIM, Winb_lo,
        (NPROJ - 4096) * DIM, 256 * DIM);
    cast_pad_kernel<<<dim3((DIM * D_INNER / 4 + 255) / 256), 256, 0, stream>>>(
        W_out, Woutb, DIM * D_INNER, DIM * D_INNER);

    // 2. in-projection GEMM: P = x @ W_in^T (1024 x 4352); B/C/dt cols 3-pass precise
    gemm_bt128<<<dim3(NPROJ_PAD / 128, L_SEQ / 128), 256, 0, stream>>>(
        xb_hi, xb_lo, Winb, Winb_lo_virt, P, DIM, NPROJ_PAD, 32);

    // 3. depthwise causal conv + SiLU
    conv_silu_kernel<<<dim3(L_SEQ), 256, 0, stream>>>(P, W_conv, b_conv, xconv);

    // 4. dt softplus + per-chunk cumsum
    dtscan_kernel<<<dim3(N_HEADS), 64, 0, stream>>>(P, dt_bias, dts, g);

    // 5. chunked selective scan
    scan_local_kernel<<<dim3(D_INNER * NCHUNK / 4), 256, 0, stream>>>(
        P, xconv, dts, A_log, Dp, yg, S);
    chunk_combine_kernel<<<dim3(D_INNER * 64 / 256), 256, 0, stream>>>(A_log, g, S);
    scan_cross_kernel<<<dim3(D_INNER * NCHUNK / 4), 256, 0, stream>>>(P, g, A_log, S, yg);

    // 6. gate + RMSNorm + bf16 cast
    rmsnorm_kernel<<<dim3(L_SEQ), 256, 0, stream>>>(yg, P, norm_w, Yb);

    // 7. out-projection GEMM: out = Y @ W_out^T (1024 x 1024)
    gemm_bt128<<<dim3(DIM / 128, L_SEQ / 128), 256, 0, stream>>>(
        Yb, (const u16*)nullptr, Woutb, (const u16*)nullptr, out, D_INNER, DIM, 9999);
}

// Round 4
// 230.740 us; speedup vs baseline: 1.4132x; 1.2041x over previous
//
#include <hip/hip_runtime.h>

typedef unsigned short u16;
typedef __attribute__((ext_vector_type(8))) short bf16x8;
typedef __attribute__((ext_vector_type(4))) float f32x4;

#define GPTR(p) ((const __attribute__((address_space(1))) void*)(p))
#define SPTR(p) ((__attribute__((address_space(3))) void*)(p))

// ---------- sizes ----------
#define L_SEQ 1024
#define DIM 1024
#define D_INNER 2048
#define D_STATE 64
#define N_HEADS 32
#define NPROJ 4256
#define NPROJ_PAD 4352   // 34 * 128
#define COL_Z 0
#define COL_X 2048
#define COL_B 4096
#define COL_C 4160
#define COL_DT 4224
#define NCHUNK 16
#define QCH 64           // chunk length

__device__ __forceinline__ u16 f2bf(float f) {
    unsigned int u = __float_as_uint(f);
    u = u + 0x7fffu + ((u >> 16) & 1u);   // RNE
    return (u16)(u >> 16);
}
__device__ __forceinline__ float bf2f(u16 h) {
    unsigned int u = ((unsigned int)h) << 16;
    return __uint_as_float(u);
}

// ---------- cast f32 -> bf16 (hi only) with zero pad ----------
__global__ __launch_bounds__(256)
void cast_pad_kernel(const float* __restrict__ in, u16* __restrict__ out,
                     int n_in, int n_out)
{
    int i = (blockIdx.x * 256 + threadIdx.x) * 4;
    if (i >= n_out) return;
    float4 v = make_float4(0.f, 0.f, 0.f, 0.f);
    if (i < n_in) v = *(const float4*)&in[i];
    u16 o[4] = { f2bf(v.x), f2bf(v.y), f2bf(v.z), f2bf(v.w) };
    *(ushort4*)&out[i] = *(ushort4*)o;
}

// ---------- cast f32 -> bf16 hi + residual lo, with zero pad ----------
__global__ __launch_bounds__(256)
void cast_split_kernel(const float* __restrict__ in, u16* __restrict__ hi,
                       u16* __restrict__ lo, int n_in, int n_out)
{
    int i = (blockIdx.x * 256 + threadIdx.x) * 4;
    if (i >= n_out) return;
    float4 v = make_float4(0.f, 0.f, 0.f, 0.f);
    if (i < n_in) v = *(const float4*)&in[i];
    float vs[4] = { v.x, v.y, v.z, v.w };
    u16 oh[4], ol[4];
    #pragma unroll
    for (int j = 0; j < 4; ++j) {
        oh[j] = f2bf(vs[j]);
        ol[j] = f2bf(vs[j] - bf2f(oh[j]));
    }
    *(ushort4*)&hi[i] = *(ushort4*)oh;
    *(ushort4*)&lo[i] = *(ushort4*)ol;
}

// ---------- bf16 MFMA GEMM: C[M,N] = A[M,K] * B[N,K]^T (m97-style) ----------
__global__ __launch_bounds__(256, 2)
void gemm_bt128(const u16* __restrict__ Ah, const u16* __restrict__ Al,
                const u16* __restrict__ Bh, const u16* __restrict__ Bl,
                float* __restrict__ C, int K, int ldc, int precise_from)
{
    __shared__ u16 As[128 * 32];
    __shared__ u16 Bs[128 * 32];
    __shared__ u16 AsL[128 * 32];
    __shared__ u16 BsL[128 * 32];
    const int tid  = threadIdx.x;
    const int wave = tid >> 6;
    const int lane = tid & 63;
    const int row0 = blockIdx.y * 128;
    const int col0 = blockIdx.x * 128;
    const int wm = (wave >> 1) * 64;
    const int wn = (wave & 1) * 64;
    const bool precise = ((int)blockIdx.x >= precise_from);

    f32x4 acc[4][4] = {};

    const int r15 = lane & 15;
    const int ko  = (lane >> 4) * 8;

    for (int kt = 0; kt < K; kt += 32) {
        #pragma unroll
        for (int call = 0; call < 2; ++call) {
            const int ob = call * 4096 + wave * 1024 + lane * 16;
            const int rr = ob >> 6;
            const int kk = (ob & 63) >> 1;
            const size_t goff = (size_t)(row0 + rr) * K + kt + kk;
            const size_t gofb = (size_t)(col0 + rr) * K + kt + kk;
            const int lofs = call * 2048 + wave * 512;
            __builtin_amdgcn_global_load_lds(GPTR(Ah + goff), SPTR(As + lofs), 16, 0, 0);
            __builtin_amdgcn_global_load_lds(GPTR(Bh + gofb), SPTR(Bs + lofs), 16, 0, 0);
            if (precise) {
                __builtin_amdgcn_global_load_lds(GPTR(Al + goff), SPTR(AsL + lofs), 16, 0, 0);
                __builtin_amdgcn_global_load_lds(GPTR(Bl + gofb), SPTR(BsL + lofs), 16, 0, 0);
            }
        }
        __syncthreads();
        bf16x8 av[4], bv[4];
        #pragma unroll
        for (int i = 0; i < 4; ++i)
            av[i] = *(const bf16x8*)&As[(wm + i * 16 + r15) * 32 + ko];
        #pragma unroll
        for (int j = 0; j < 4; ++j)
            bv[j] = *(const bf16x8*)&Bs[(wn + j * 16 + r15) * 32 + ko];
        if (precise) {
            bf16x8 avl[4], bvl[4];
            #pragma unroll
            for (int i = 0; i < 4; ++i)
                avl[i] = *(const bf16x8*)&AsL[(wm + i * 16 + r15) * 32 + ko];
            #pragma unroll
            for (int j = 0; j < 4; ++j)
                bvl[j] = *(const bf16x8*)&BsL[(wn + j * 16 + r15) * 32 + ko];
            #pragma unroll
            for (int i = 0; i < 4; ++i)
                #pragma unroll
                for (int j = 0; j < 4; ++j) {
                    acc[i][j] = __builtin_amdgcn_mfma_f32_16x16x32_bf16(av[i],  bv[j],  acc[i][j], 0, 0, 0);
                    acc[i][j] = __builtin_amdgcn_mfma_f32_16x16x32_bf16(av[i],  bvl[j], acc[i][j], 0, 0, 0);
                    acc[i][j] = __builtin_amdgcn_mfma_f32_16x16x32_bf16(avl[i], bv[j],  acc[i][j], 0, 0, 0);
                }
        } else {
            #pragma unroll
            for (int i = 0; i < 4; ++i)
                #pragma unroll
                for (int j = 0; j < 4; ++j)
                    acc[i][j] = __builtin_amdgcn_mfma_f32_16x16x32_bf16(av[i], bv[j], acc[i][j], 0, 0, 0);
        }
        __syncthreads();
    }

    const int cl = lane & 15;
    const int rg = (lane >> 4) * 4;
    #pragma unroll
    for (int i = 0; i < 4; ++i)
        #pragma unroll
        for (int j = 0; j < 4; ++j)
            #pragma unroll
            for (int reg = 0; reg < 4; ++reg) {
                const int rrow = row0 + wm + i * 16 + rg + reg;
                const int ccol = col0 + wn + j * 16 + cl;
                C[(size_t)rrow * ldc + ccol] = acc[i][j][reg];
            }
}

// ---------- causal depthwise conv(4) + SiLU; also repacks B/C columns ----------
__global__ __launch_bounds__(256)
void conv_silu_kernel(const float* __restrict__ P,
                      const float* __restrict__ Wc,
                      const float* __restrict__ bc,
                      float* __restrict__ xconv,
                      float* __restrict__ BCp)
{
    const int t = blockIdx.x;
    const int tid = threadIdx.x;
    const int c0 = tid * 8;

    float acc[8];
    #pragma unroll
    for (int j = 0; j < 8; ++j) acc[j] = bc[c0 + j];

    #pragma unroll
    for (int k = 0; k < 4; ++k) {
        const int tt = t - 3 + k;
        if (tt >= 0) {
            const float* row = P + (size_t)tt * NPROJ_PAD + COL_X + c0;
            float4 a0 = *(const float4*)row;
            float4 a1 = *(const float4*)(row + 4);
            float xv[8] = { a0.x, a0.y, a0.z, a0.w, a1.x, a1.y, a1.z, a1.w };
            #pragma unroll
            for (int j = 0; j < 8; ++j)
                acc[j] = fmaf(xv[j], Wc[(c0 + j) * 4 + k], acc[j]);
        }
    }
    float o[8];
    #pragma unroll
    for (int j = 0; j < 8; ++j) {
        const float v = acc[j];
        o[j] = v / (1.f + __expf(-v));         // SiLU
    }
    float* dst = xconv + (size_t)t * D_INNER + c0;
    *(float4*)dst       = make_float4(o[0], o[1], o[2], o[3]);
    *(float4*)(dst + 4) = make_float4(o[4], o[5], o[6], o[7]);

    if (tid < 128)   // repack B|C columns contiguous: BCp[t][0..63]=B, [64..127]=C
        BCp[t * 128 + tid] = P[(size_t)t * NPROJ_PAD + COL_B + tid];
}

// ---------- dt softplus + per-chunk inclusive cumsum; transposed outputs ----------
__global__ __launch_bounds__(64)
void dtscan_kernel(const float* __restrict__ P, const float* __restrict__ dtb,
                   float* __restrict__ dtsT, float* __restrict__ gT)
{
    const int idx = blockIdx.x;        // h*16 + chunk
    const int h = idx >> 4;
    const int c = idx & 15;
    const int lane = threadIdx.x;
    const int t = c * QCH + lane;
    float v = P[(size_t)t * NPROJ_PAD + COL_DT + h] + dtb[h];
    v = (v > 15.f) ? v : __logf(1.f + __expf(v));
    dtsT[h * L_SEQ + t] = v;
    #pragma unroll
    for (int off = 1; off < 64; off <<= 1) {
        const float u = __shfl_up(v, off);
        if (lane >= off) v += u;
    }
    gT[h * L_SEQ + t] = v;
}

// ---------- pass 1: local chunk scan. lane = n; wave = (hd, chunk) ----------
__global__ __launch_bounds__(128, 4)
void scan_local_kernel(const float* __restrict__ BCp,
                       const float* __restrict__ xconv,
                       const float* __restrict__ dtsT,
                       const float* __restrict__ A_log,
                       const float* __restrict__ Dp,
                       float* __restrict__ yg,    // [hd][t] partial
                       float* __restrict__ S)     // [hd][chunk][n] local final state
{
    __shared__ float ptile[2][32][65];
    const int wv = threadIdx.x >> 6;
    const int lane = threadIdx.x & 63;
    const int w = blockIdx.x * 2 + wv;
    const int hd = w >> 4;
    const int chunk = w & 15;
    const int h = hd >> 6;
    const int t0 = chunk * QCH;
    const int l31 = lane & 31;

    const float Av = -__expf(A_log[(size_t)hd * 64 + lane]);
    const float Dv = Dp[hd];
    float s = 0.f;

    // preload both phases' dt / x values (lane l31 holds step t0+p*32+l31)
    const float dtv0 = dtsT[h * L_SEQ + t0 + l31];
    const float dtv1 = dtsT[h * L_SEQ + t0 + 32 + l31];
    const float xvv0 = xconv[(size_t)(t0 + l31) * D_INNER + hd];
    const float xvv1 = xconv[(size_t)(t0 + 32 + l31) * D_INNER + hd];

    #pragma unroll
    for (int p = 0; p < 2; ++p) {
        const float dtv = p ? dtv1 : dtv0;
        const float xvv = p ? xvv1 : xvv0;
        const float* bc = BCp + (size_t)(t0 + p * 32) * 128;
        #pragma unroll
        for (int i = 0; i < 32; ++i) {
            const float dt_i = __shfl(dtv, i);
            const float xv_i = __shfl(xvv, i);
            const float Bv = bc[i * 128 + lane];
            const float Cv = bc[i * 128 + 64 + lane];
            s = fmaf(__expf(dt_i * Av), s, Bv * xv_i);
            ptile[wv][i][lane] = s * Cv;
        }
        // per-wave deferred reduce (no barrier: ptile slice is wave-private)
        float ss = 0.f;
        const int tr = l31;
        const int nh = (lane >> 5) * 32;
        #pragma unroll
        for (int n = 0; n < 32; ++n) ss += ptile[wv][tr][nh + n];
        ss += __shfl_xor(ss, 32);
        if (lane < 32)
            yg[(size_t)hd * L_SEQ + t0 + p * 32 + lane] = ss + Dv * xvv;
    }
    S[((size_t)hd * NCHUNK + chunk) * 64 + lane] = s;
}

// ---------- pass 2: chunk-state carry (in place: S -> chunk entry states) ----------
__global__ __launch_bounds__(256)
void chunk_combine_kernel(const float* __restrict__ A_log,
                          const float* __restrict__ gT,
                          float* __restrict__ S)
{
    const int tid = blockIdx.x * 256 + threadIdx.x;   // hd*64 + n
    const int hd = tid >> 6;
    const int n  = tid & 63;
    const int h  = hd >> 6;
    const float Av = -__expf(A_log[(size_t)hd * 64 + n]);
    float H = 0.f;
    for (int c = 0; c < NCHUNK; ++c) {
        const float Gc = gT[h * L_SEQ + c * QCH + QCH - 1];
        const size_t idx = ((size_t)hd * NCHUNK + c) * 64 + n;
        const float Sl = S[idx];
        S[idx] = H;                       // entry state for chunk c
        H = __expf(Av * Gc) * H + Sl;
    }
}

// ---------- pass 3 (MFMA): y[t,d] += sum_n C'[t,n] * H[n,d] per (h,chunk) ----------
__global__ __launch_bounds__(256, 2)
void scan_cross_mfma(const float* __restrict__ P,
                     const float* __restrict__ gT,
                     const float* __restrict__ A_log,
                     const float* __restrict__ S,   // entry states [hd][chunk][n]
                     float* __restrict__ yg)        // [hd][t] +=
{
    const int wv = threadIdx.x >> 6;
    const int lane = threadIdx.x & 63;
    const int idx = blockIdx.x * 4 + wv;   // h*16 + chunk
    const int h = idx >> 4;
    const int chunk = idx & 15;
    const int t0 = chunk * QCH;
    const int l15 = lane & 15;
    const int lk  = (lane >> 4) * 8;       // k-offset base within 32-k step

    // decay rates for this lane's two k-slices (A uniform over d; use d=0 row)
    float Av8[2][8];
    #pragma unroll
    for (int sstep = 0; sstep < 2; ++sstep)
        #pragma unroll
        for (int q = 0; q < 8; ++q)
            Av8[sstep][q] = -__expf(A_log[(size_t)h * 4096 + sstep * 32 + lk + q]);

    // A-operand frags: A[d][n] = H[n][d] = S entry state
    bf16x8 aH[4][2];
    #pragma unroll
    for (int i = 0; i < 4; ++i)
        #pragma unroll
        for (int sstep = 0; sstep < 2; ++sstep) {
            const int d = i * 16 + l15;
            const int n0 = sstep * 32 + lk;
            const float* src = S + ((size_t)(h * 64 + d) * NCHUNK + chunk) * 64 + n0;
            const float4 a = *(const float4*)src;
            const float4 b = *(const float4*)(src + 4);
            const float v[8] = { a.x, a.y, a.z, a.w, b.x, b.y, b.z, b.w };
            bf16x8 r;
            #pragma unroll
            for (int q = 0; q < 8; ++q) r[q] = (short)f2bf(v[q]);
            aH[i][sstep] = r;
        }

    // B-operand frags: B[k=n][col=t] = C'[t][n] = C[t][n]*exp(Av_n*g_t)
    bf16x8 bC[4][2];
    #pragma unroll
    for (int j = 0; j < 4; ++j) {
        const int t = t0 + j * 16 + l15;
        const float g = gT[h * L_SEQ + t];
        #pragma unroll
        for (int sstep = 0; sstep < 2; ++sstep) {
            const int n0 = sstep * 32 + lk;
            const float* src = P + (size_t)t * NPROJ_PAD + COL_C + n0;
            const float4 a = *(const float4*)src;
            const float4 b = *(const float4*)(src + 4);
            const float v[8] = { a.x, a.y, a.z, a.w, b.x, b.y, b.z, b.w };
            bf16x8 r;
            #pragma unroll
            for (int q = 0; q < 8; ++q)
                r[q] = (short)f2bf(v[q] * __expf(Av8[sstep][q] * g));
            bC[j][sstep] = r;
        }
    }

    f32x4 acc[4][4] = {};
    #pragma unroll
    for (int sstep = 0; sstep < 2; ++sstep)
        #pragma unroll
        for (int i = 0; i < 4; ++i)
            #pragma unroll
            for (int j = 0; j < 4; ++j)
                acc[i][j] = __builtin_amdgcn_mfma_f32_16x16x32_bf16(aH[i][sstep], bC[j][sstep], acc[i][j], 0, 0, 0);

    // epilogue: yg[h*64 + row][t0 + col] += acc  (row=d, col=t)
    const int rg = (lane >> 4) * 4;
    #pragma unroll
    for (int i = 0; i < 4; ++i)
        #pragma unroll
        for (int j = 0; j < 4; ++j)
            #pragma unroll
            for (int r = 0; r < 4; ++r) {
                const int d = i * 16 + rg + r;
                const int t = j * 16 + l15;
                float* p = yg + (size_t)(h * 64 + d) * L_SEQ + t0 + t;
                *p += acc[i][j][r];
            }
}

// ---------- RMSNorm + gate + cast to bf16 ----------
__global__ __launch_bounds__(256)
void rmsnorm_kernel(const float* __restrict__ yg,   // [hd][t]
                    const float* __restrict__ P,    // z columns
                    const float* __restrict__ nw,
                    u16* __restrict__ Yb)           // [t][hd] bf16
{
    __shared__ float red[4];
    const int t = blockIdx.x;
    const int tid = threadIdx.x;
    const int c0 = tid * 8;
    const float* zrow = P + (size_t)t * NPROJ_PAD + COL_Z + c0;
    const float4 z0 = *(const float4*)zrow;
    const float4 z1 = *(const float4*)(zrow + 4);
    const float zz[8] = { z0.x, z0.y, z0.z, z0.w, z1.x, z1.y, z1.z, z1.w };
    float v[8];
    float ss = 0.f;
    #pragma unroll
    for (int j = 0; j < 8; ++j) {
        const float yv = yg[(size_t)(c0 + j) * L_SEQ + t];
        const float z = zz[j];
        const float gated = yv * (z / (1.f + __expf(-z)));
        v[j] = gated;
        ss += gated * gated;
    }
    #pragma unroll
    for (int off = 32; off > 0; off >>= 1) ss += __shfl_xor(ss, off);
    const int wave = tid >> 6;
    if ((tid & 63) == 0) red[wave] = ss;
    __syncthreads();
    const float total = red[0] + red[1] + red[2] + red[3];
    const float scale = rsqrtf(total * (1.f / D_INNER) + 1e-6f);
    u16 o[8];
    #pragma unroll
    for (int j = 0; j < 8; ++j)
        o[j] = f2bf(v[j] * scale * nw[c0 + j]);
    *(uint4*)&Yb[(size_t)t * D_INNER + c0] = *(uint4*)o;
}

// ---------- launcher ----------
extern "C" void kernel_launch(void* const* d_in, const int* in_sizes, int n_in,
                              void* d_out, int out_size, void* d_ws, size_t ws_size,
                              hipStream_t stream)
{
    const float* x      = (const float*)d_in[0];
    const float* W_in   = (const float*)d_in[1];
    const float* W_conv = (const float*)d_in[2];
    const float* b_conv = (const float*)d_in[3];
    const float* A_log  = (const float*)d_in[4];
    const float* Dp     = (const float*)d_in[5];
    const float* dt_bias= (const float*)d_in[6];
    const float* norm_w = (const float*)d_in[7];
    const float* W_out  = (const float*)d_in[8];
    float* out = (float*)d_out;

    char* w = (char*)d_ws;
    u16*   xb_hi  = (u16*)(w);                         //  2.0 MiB (dead after GEMM1)
    u16*   xb_lo  = (u16*)(w + (2u  << 20));           //  2.0 MiB (dead after GEMM1)
    u16*   Yb     = (u16*)(w);                         //  4.0 MiB (overlaps xb_*)
    u16*   Winb   = (u16*)(w + (4u  << 20));           //  8.5 MiB (dead after GEMM1)
    float* S      = (float*)(w + (4u  << 20));         //  8.4 MiB (overlaps Winb)
    u16*   Winb_lo= (u16*)(w + (13u << 20));           //  0.5 MiB
    u16*   Woutb  = (u16*)(w + (14u << 20));           //  4.0 MiB
    float* P      = (float*)(w + (18u << 20));         // 17.0 MiB (1024x4352)
    float* xconv  = (float*)(w + (35u << 20));         //  8.0 MiB
    float* dtsT   = (float*)(w + (43u << 20));         //  0.13 MiB [h][t]
    float* gT     = (float*)(w + (43u << 20) + (512u << 10)); // 0.13 MiB [h][t]
    float* BCp    = (float*)(w + (44u << 20));         //  0.5 MiB [t][128]
    float* yg     = (float*)(w + (45u << 20));         //  8.0 MiB [hd][t]

    const u16* Winb_lo_virt = Winb_lo - (size_t)4096 * DIM;

    // 1. casts
    cast_split_kernel<<<dim3((DIM * L_SEQ / 4 + 255) / 256), 256, 0, stream>>>(
        x, xb_hi, xb_lo, DIM * L_SEQ, DIM * L_SEQ);
    cast_pad_kernel<<<dim3((NPROJ_PAD * DIM / 4 + 255) / 256), 256, 0, stream>>>(
        W_in, Winb, NPROJ * DIM, NPROJ_PAD * DIM);
    cast_split_kernel<<<dim3((256 * DIM / 4 + 255) / 256), 256, 0, stream>>>(
        W_in + (size_t)4096 * DIM, Winb + (size_t)4096 * DIM, Winb_lo,
        (NPROJ - 4096) * DIM, 256 * DIM);
    cast_pad_kernel<<<dim3((DIM * D_INNER / 4 + 255) / 256), 256, 0, stream>>>(
        W_out, Woutb, DIM * D_INNER, DIM * D_INNER);

    // 2. in-projection GEMM: P = x @ W_in^T (1024 x 4352); B/C/dt cols 3-pass precise
    gemm_bt128<<<dim3(NPROJ_PAD / 128, L_SEQ / 128), 256, 0, stream>>>(
        xb_hi, xb_lo, Winb, Winb_lo_virt, P, DIM, NPROJ_PAD, 32);

    // 3. depthwise causal conv + SiLU + B/C repack
    conv_silu_kernel<<<dim3(L_SEQ), 256, 0, stream>>>(P, W_conv, b_conv, xconv, BCp);

    // 4. dt softplus + per-chunk cumsum (transposed layouts)
    dtscan_kernel<<<dim3(N_HEADS * NCHUNK), 64, 0, stream>>>(P, dt_bias, dtsT, gT);

    // 5. chunked selective scan
    scan_local_kernel<<<dim3(D_INNER * NCHUNK / 2), 128, 0, stream>>>(
        BCp, xconv, dtsT, A_log, Dp, yg, S);
    chunk_combine_kernel<<<dim3(D_INNER * 64 / 256), 256, 0, stream>>>(A_log, gT, S);
    scan_cross_mfma<<<dim3(N_HEADS * NCHUNK / 4), 256, 0, stream>>>(P, gT, A_log, S, yg);

    // 6. gate + RMSNorm + bf16 cast
    rmsnorm_kernel<<<dim3(L_SEQ), 256, 0, stream>>>(yg, P, norm_w, Yb);

    // 7. out-projection GEMM: out = Y @ W_out^T (1024 x 1024)
    gemm_bt128<<<dim3(DIM / 128, L_SEQ / 128), 256, 0, stream>>>(
        Yb, (const u16*)nullptr, Woutb, (const u16*)nullptr, out, D_INNER, DIM, 9999);
}